// Round 11
// baseline (62.403 us; speedup 1.0000x reference)
//
#include <hip/hip_runtime.h>
#include <math.h>

#define N_ROWS 1024
#define RANK   8
#define M_COLS 4096

#define R_ROWS   2      // n-rows per thread
#define T_PTS    8      // m-points per thread (rotation-amortized)
#define M_STRIDE 512    // stride-interleaved points => coalesced 8B/lane

// Static device scratch (fully overwritten every call before read).
__device__ float  g_Wp [N_ROWS * RANK];   // softplus(W), 32 KB
__device__ float2 g_Hft[RANK * M_COLS];   // full FFT of softplus(H), 256 KB

// fast softplus: 2 trans + ~4 VALU. exact for x>20; inputs are ~N(0,1).
__device__ __forceinline__ float softplus_f(float x) {
    float t = __expf(x);
    float r = 0.69314718056f * __log2f(1.0f + t);
    return (x > 20.0f) ? x : r;
}
// hw trig: v_sin/v_cos compute sin/cos(2*pi*x), x in revolutions.
__device__ __forceinline__ float sin_rev(float x) { return __builtin_amdgcn_sinf(x); }
__device__ __forceinline__ float cos_rev(float x) { return __builtin_amdgcn_cosf(x); }
__device__ __forceinline__ float fract_f(float x) { return __builtin_amdgcn_fractf(x); }
// force a block-uniform float into an SGPR (frees a VGPR; VALU reads it as the
// one allowed scalar operand)
__device__ __forceinline__ float rfl(float x) {
    return __int_as_float(__builtin_amdgcn_readfirstlane(__float_as_int(x)));
}

// ---------------------------------------------------------------------------
// Fused FFT: softplus(H) + 64x64 Cooley-Tukey DFT -> g_Hft. (unchanged)
// ---------------------------------------------------------------------------
__global__ void fft_fused(const float* __restrict__ H,
                          const float* __restrict__ W) {
    __shared__ float  sHs[M_COLS];        // 16 KB
    __shared__ float2 sY[4 * 64];         // [j][k0], 2 KB

    int tid = threadIdx.x;
    int d   = blockIdx.x >> 4;
    int m0b = (blockIdx.x & 15) << 2;

    if (blockIdx.x < 32) {                // Wp side-job (no dependency)
        int t = blockIdx.x * 256 + tid;   // < 8192
        g_Wp[t] = softplus_f(W[t]);
    }

    const float4* Hrow4 = (const float4*)(H + d * M_COLS);
    #pragma unroll
    for (int p = 0; p < 4; ++p) {
        int i = p * 256 + tid;            // 1024 float4 per row
        float4 h4 = Hrow4[i];
        sHs[i*4+0] = softplus_f(h4.x);
        sHs[i*4+1] = softplus_f(h4.y);
        sHs[i*4+2] = softplus_f(h4.z);
        sHs[i*4+3] = softplus_f(h4.w);
    }
    __syncthreads();

    {   // stage A
        int k0 = tid & 63, j = tid >> 6;
        int m0 = m0b + j;
        float mrev = (float)m0 * (1.0f / 64.0f);
        float rr =  cos_rev(mrev);
        float ri = -sin_rev(mrev);        // step = e^{-2pi i m0/64}
        float twr = 1.0f, twi = 0.0f;
        float ar = 0.0f, ai = 0.0f;
        #pragma unroll
        for (int k1 = 0; k1 < 64; ++k1) {
            float v = sHs[(k1 << 6) + k0];
            ar = fmaf(v, twr, ar);
            ai = fmaf(v, twi, ai);
            float nr = fmaf(twr, rr, -(twi * ri));
            twi      = fmaf(twr, ri,   twi * rr);
            twr = nr;
        }
        sY[(j << 6) + k0] = make_float2(ar, ai);
    }
    __syncthreads();

    {   // stage B
        int m1 = tid & 63, j = tid >> 6;
        int m  = (m1 << 6) + m0b + j;
        float mrev = (float)m * (1.0f / 4096.0f);
        float rr =  cos_rev(mrev);
        float ri = -sin_rev(mrev);        // step = e^{-2pi i m/4096}
        float twr = 1.0f, twi = 0.0f;
        float ar = 0.0f, ai = 0.0f;
        #pragma unroll
        for (int k0 = 0; k0 < 64; ++k0) {
            float2 y = sY[(j << 6) + k0];
            ar = fmaf(y.x, twr, fmaf(-y.y, twi, ar));
            ai = fmaf(y.x, twi, fmaf( y.y, twr, ai));
            float nr = fmaf(twr, rr, -(twi * ri));
            twi      = fmaf(twr, ri,   twi * rr);
            twr = nr;
        }
        g_Hft[d * M_COLS + m] = make_float2(ar, ai);
    }
}

// ---------------------------------------------------------------------------
// Main: j-OUTER / d-INNER, 16 independent phasor chains (max ILP), rotation
// steps in SGPRs (readfirstlane), h prefetched one j ahead, even/odd split
// accumulators. __launch_bounds__(256,4) = 128-VGPR cap (grid gives 4
// waves/SIMD); est. live VGPRs ~95 -> NO spill (R8 lesson: default target
// spilled this structure at 64 VGPRs).
// ---------------------------------------------------------------------------
__global__ __launch_bounds__(256, 4)
void shiftnmf_main(const float* __restrict__ tau,
                   float* __restrict__ out) {
    int tid = threadIdx.x;
    int m0  = blockIdx.x * 256 + tid;     // 0..511
    int n0  = blockIdx.y * R_ROWS;

    float fm0 = (float)m0 * (1.0f / (float)M_COLS);

    // 16 phasor chains uw[r][d]; step v[r][d] -> SGPRs (block-uniform)
    float uwr[R_ROWS][RANK], uwi[R_ROWS][RANK];
    float svr[R_ROWS][RANK], svi[R_ROWS][RANK];
    #pragma unroll
    for (int r = 0; r < R_ROWS; ++r) {
        int n = n0 + r;
        #pragma unroll
        for (int d = 0; d < RANK; ++d) {
            float w  = g_Wp[n * RANK + d];            // block-uniform load
            float tv = tau [n * RANK + d];            // block-uniform load
            float sv = fract_f(tv * (1.0f / 8.0f));   // 512/4096
            svr[r][d] = rfl(cos_rev(sv));             // step = e^{+i2pi tau*512/M}
            svi[r][d] = rfl(sin_rev(sv));
            float r0 = fract_f(tv * fm0);
            uwr[r][d] = w * cos_rev(r0);              // uw = w*e^{+i2pi tau*m0/M}
            uwi[r][d] = w * sin_rev(r0);
        }
    }

    float2 hc[RANK], hn[RANK];
    #pragma unroll
    for (int d = 0; d < RANK; ++d)
        hc[d] = g_Hft[d * M_COLS + m0];

    float acc[R_ROWS][T_PTS];
    #pragma unroll
    for (int j = 0; j < T_PTS; ++j) {
        if (j + 1 < T_PTS) {                          // prefetch next j's h
            #pragma unroll
            for (int d = 0; d < RANK; ++d)
                hn[d] = g_Hft[d * M_COLS + m0 + (j + 1) * M_STRIDE];
        }
        #pragma unroll
        for (int r = 0; r < R_ROWS; ++r) {            // split-chain accumulate
            float a0 = 0.0f, a1 = 0.0f;
            #pragma unroll
            for (int d = 0; d < RANK; d += 2) {
                a0 = fmaf(uwr[r][d],   hc[d].x,   fmaf(uwi[r][d],   hc[d].y,   a0));
                a1 = fmaf(uwr[r][d+1], hc[d+1].x, fmaf(uwi[r][d+1], hc[d+1].y, a1));
            }
            acc[r][j] = a0 + a1;
        }
        if (j + 1 < T_PTS) {
            #pragma unroll
            for (int r = 0; r < R_ROWS; ++r)          // 16 independent rotations
                #pragma unroll
                for (int d = 0; d < RANK; ++d) {
                    float nr  = fmaf(uwr[r][d], svr[r][d], -(uwi[r][d] * svi[r][d]));
                    uwi[r][d] = fmaf(uwr[r][d], svi[r][d],   uwi[r][d] * svr[r][d]);
                    uwr[r][d] = nr;
                }
            #pragma unroll
            for (int d = 0; d < RANK; ++d) hc[d] = hn[d];
        }
    }

    #pragma unroll
    for (int r = 0; r < R_ROWS; ++r) {
        float* op = out + (n0 + r) * M_COLS + m0;
        #pragma unroll
        for (int j = 0; j < T_PTS; ++j)
            op[j * M_STRIDE] = acc[r][j];
    }
}

extern "C" void kernel_launch(void* const* d_in, const int* in_sizes, int n_in,
                              void* d_out, int out_size, void* d_ws, size_t ws_size,
                              hipStream_t stream) {
    const float* W   = (const float*)d_in[0];   // [1024, 8]
    const float* H   = (const float*)d_in[1];   // [8, 4096]
    const float* tau = (const float*)d_in[2];   // [1024, 8]

    fft_fused<<<dim3(RANK * 16), dim3(256), 0, stream>>>(H, W);

    dim3 grid(M_COLS / (256 * T_PTS), N_ROWS / R_ROWS);  // (2, 512)
    shiftnmf_main<<<grid, dim3(256), 0, stream>>>(tau, (float*)d_out);
}

// Round 12
// 20.201 us; speedup vs baseline: 3.0891x; 3.0891x over previous
//
#include <hip/hip_runtime.h>
#include <math.h>

#define N_ROWS 1024
#define RANK   8
#define M_COLS 4096

#define R_ROWS   2      // n-rows per thread
#define T_PTS    4      // points per thread in [1,2048], stride 512
#define M_STRIDE 512

// Static device scratch (fully overwritten every call before read).
__device__ float  g_Wp [N_ROWS * RANK];   // softplus(W), 32 KB
__device__ float2 g_Hft[RANK * M_COLS];   // full FFT of softplus(H), 256 KB

// fast softplus: 2 trans + ~4 VALU. exact for x>20; inputs are ~N(0,1).
__device__ __forceinline__ float softplus_f(float x) {
    float t = __expf(x);
    float r = 0.69314718056f * __log2f(1.0f + t);
    return (x > 20.0f) ? x : r;
}
// hw trig: v_sin/v_cos compute sin/cos(2*pi*x), x in revolutions.
__device__ __forceinline__ float sin_rev(float x) { return __builtin_amdgcn_sinf(x); }
__device__ __forceinline__ float cos_rev(float x) { return __builtin_amdgcn_cosf(x); }
__device__ __forceinline__ float fract_f(float x) { return __builtin_amdgcn_fractf(x); }
// block-uniform float -> SGPR
__device__ __forceinline__ float rfl(float x) {
    return __int_as_float(__builtin_amdgcn_readfirstlane(__float_as_int(x)));
}

// ---------------------------------------------------------------------------
// Fused FFT: softplus(H) + 64x64 Cooley-Tukey DFT -> g_Hft. (R7-proven, unchanged)
// ---------------------------------------------------------------------------
__global__ void fft_fused(const float* __restrict__ H,
                          const float* __restrict__ W) {
    __shared__ float  sHs[M_COLS];        // 16 KB
    __shared__ float2 sY[4 * 64];         // [j][k0], 2 KB

    int tid = threadIdx.x;
    int d   = blockIdx.x >> 4;
    int m0b = (blockIdx.x & 15) << 2;

    if (blockIdx.x < 32) {                // Wp side-job (no dependency)
        int t = blockIdx.x * 256 + tid;   // < 8192
        g_Wp[t] = softplus_f(W[t]);
    }

    const float4* Hrow4 = (const float4*)(H + d * M_COLS);
    #pragma unroll
    for (int p = 0; p < 4; ++p) {
        int i = p * 256 + tid;            // 1024 float4 per row
        float4 h4 = Hrow4[i];
        sHs[i*4+0] = softplus_f(h4.x);
        sHs[i*4+1] = softplus_f(h4.y);
        sHs[i*4+2] = softplus_f(h4.z);
        sHs[i*4+3] = softplus_f(h4.w);
    }
    __syncthreads();

    {   // stage A
        int k0 = tid & 63, j = tid >> 6;
        int m0 = m0b + j;
        float mrev = (float)m0 * (1.0f / 64.0f);
        float rr =  cos_rev(mrev);
        float ri = -sin_rev(mrev);        // step = e^{-2pi i m0/64}
        float twr = 1.0f, twi = 0.0f;
        float ar = 0.0f, ai = 0.0f;
        #pragma unroll
        for (int k1 = 0; k1 < 64; ++k1) {
            float v = sHs[(k1 << 6) + k0];
            ar = fmaf(v, twr, ar);
            ai = fmaf(v, twi, ai);
            float nr = fmaf(twr, rr, -(twi * ri));
            twi      = fmaf(twr, ri,   twi * rr);
            twr = nr;
        }
        sY[(j << 6) + k0] = make_float2(ar, ai);
    }
    __syncthreads();

    {   // stage B
        int m1 = tid & 63, j = tid >> 6;
        int m  = (m1 << 6) + m0b + j;
        float mrev = (float)m * (1.0f / 4096.0f);
        float rr =  cos_rev(mrev);
        float ri = -sin_rev(mrev);        // step = e^{-2pi i m/4096}
        float twr = 1.0f, twi = 0.0f;
        float ar = 0.0f, ai = 0.0f;
        #pragma unroll
        for (int k0 = 0; k0 < 64; ++k0) {
            float2 y = sY[(j << 6) + k0];
            ar = fmaf(y.x, twr, fmaf(-y.y, twi, ar));
            ai = fmaf(y.x, twi, fmaf( y.y, twr, ai));
            float nr = fmaf(twr, rr, -(twi * ri));
            twi      = fmaf(twr, ri,   twi * rr);
            twr = nr;
        }
        g_Hft[d * M_COLS + m] = make_float2(ar, ai);
    }
}

// ---------------------------------------------------------------------------
// Main with Hermitian mirroring. For m in [1,2048] (T_PTS=4, stride 512):
//   u = e^{+i 2pi tau m/M} (unit), z = conj(u)*h:
//     zr = ur*hr + ui*hi, zi = ur*hi - ui*hr
//   Re V[n,m]      += w * zr
//   Re V[n,4096-m] += wcr*zr + wci*zi,   (wcr,wci) = w * e^{-2pi i tau}
// (Hft[M-m] = conj(Hft[m]) since softplus(H) is real.) Column 0 is a 1-lane
// direct sum; column 2048 is self-mirror (formulas provably equal).
// Halves Hft loads AND L2 traffic per output vs R7 at equal register cost.
// d-outer, ~40 live VGPRs, default compile (R8/R11 lesson: no big arrays).
// ---------------------------------------------------------------------------
__global__ void shiftnmf_main(const float* __restrict__ tau,
                              float* __restrict__ out) {
    int tid = threadIdx.x;
    int m0  = blockIdx.x * 256 + tid;     // 0..511 ; m_j = 1 + m0 + j*512
    int n0  = blockIdx.y * R_ROWS;

    float fm0 = (float)(1 + m0) * (1.0f / (float)M_COLS);

    float accm[R_ROWS][T_PTS];            // direct outputs, m
    float accx[R_ROWS][T_PTS];            // mirror outputs, 4096-m
    #pragma unroll
    for (int r = 0; r < R_ROWS; ++r)
        #pragma unroll
        for (int j = 0; j < T_PTS; ++j) { accm[r][j] = 0.0f; accx[r][j] = 0.0f; }

    #pragma unroll
    for (int d = 0; d < RANK; ++d) {
        float ur[R_ROWS], ui[R_ROWS];                 // unit phasor (per-lane)
        float vrs[R_ROWS], vis[R_ROWS];               // step, SGPR
        float ws[R_ROWS], wcr[R_ROWS], wci[R_ROWS];   // weights, SGPR
        #pragma unroll
        for (int r = 0; r < R_ROWS; ++r) {
            int n    = n0 + r;
            float w  = g_Wp[n * RANK + d];            // block-uniform
            float tv = tau [n * RANK + d];            // block-uniform
            ws[r] = rfl(w);
            float rv = fract_f(tv * 0.125f);          // 512/4096 rev per step
            vrs[r] = rfl(cos_rev(rv));                // v = e^{+i 2pi tau/8}
            vis[r] = rfl(sin_rev(rv));
            float rc = fract_f(-tv);                  // e^{-2pi i tau}
            float cr = cos_rev(rc), ci = sin_rev(rc);
            wcr[r] = rfl(w * cr);
            wci[r] = rfl(w * ci);
            float r0 = fract_f(tv * fm0);
            ur[r] = cos_rev(r0);                      // u = e^{+i 2pi tau m_0/M}
            ui[r] = sin_rev(r0);
        }

        const float2* hp = g_Hft + d * M_COLS + 1 + m0;
        #pragma unroll
        for (int j = 0; j < T_PTS; ++j) {
            float2 h = hp[j * M_STRIDE];              // coalesced, L2-resident
            #pragma unroll
            for (int r = 0; r < R_ROWS; ++r) {
                float t1 = ui[r] * h.y;
                float zr = fmaf(ur[r], h.x, t1);      // Re(conj(u)h)
                float t2 = ui[r] * h.x;
                float zi = fmaf(ur[r], h.y, -t2);     // Im(conj(u)h)
                accm[r][j] = fmaf(ws[r],  zr, accm[r][j]);
                accx[r][j] = fmaf(wcr[r], zr, fmaf(wci[r], zi, accx[r][j]));
                if (j < T_PTS - 1) {                  // u *= v (skip dead last)
                    float nr = fmaf(ur[r], vrs[r], -(ui[r] * vis[r]));
                    ui[r]    = fmaf(ur[r], vis[r],   ui[r] * vrs[r]);
                    ur[r]    = nr;
                }
            }
        }
    }

    #pragma unroll
    for (int r = 0; r < R_ROWS; ++r) {
        float* op = out + (n0 + r) * M_COLS;
        #pragma unroll
        for (int j = 0; j < T_PTS; ++j)
            op[1 + m0 + j * M_STRIDE] = accm[r][j];   // m in [1,2048]
        #pragma unroll
        for (int j = 0; j < T_PTS; ++j)
            op[4095 - m0 - j * M_STRIDE] = accx[r][j]; // 4096-m in [2048,4095]
    }

    if (blockIdx.x == 0 && tid == 0) {                // column 0, direct
        #pragma unroll
        for (int r = 0; r < R_ROWS; ++r) {
            int n = n0 + r;
            float a = 0.0f;
            #pragma unroll
            for (int d = 0; d < RANK; ++d)
                a = fmaf(g_Wp[n * RANK + d], g_Hft[d * M_COLS].x, a);
            out[n * M_COLS] = a;
        }
    }
}

extern "C" void kernel_launch(void* const* d_in, const int* in_sizes, int n_in,
                              void* d_out, int out_size, void* d_ws, size_t ws_size,
                              hipStream_t stream) {
    const float* W   = (const float*)d_in[0];   // [1024, 8]
    const float* H   = (const float*)d_in[1];   // [8, 4096]
    const float* tau = (const float*)d_in[2];   // [1024, 8]

    fft_fused<<<dim3(RANK * 16), dim3(256), 0, stream>>>(H, W);

    dim3 grid(2, N_ROWS / R_ROWS);               // (2, 512) = 4 waves/SIMD
    shiftnmf_main<<<grid, dim3(256), 0, stream>>>(tau, (float*)d_out);
}

// Round 13
// 19.205 us; speedup vs baseline: 3.2493x; 1.0519x over previous
//
#include <hip/hip_runtime.h>
#include <math.h>

#define N_ROWS 1024
#define RANK   8
#define M_COLS 4096

#define R_ROWS   2      // n-rows per thread
#define T_PTS    2      // direct points per thread in [1,2048], stride 1024
#define M_STRIDE 1024

// Static device scratch (fully overwritten every call before read).
__device__ float2 g_Hft[RANK * M_COLS];    // full FFT of softplus(H), 256 KB
__device__ float4 g_Tab4[N_ROWS * RANK];   // {vr, vi, wcr, wci} per (n,d), 128 KB
__device__ float2 g_Tab2[N_ROWS * RANK];   // {ws, tau}          per (n,d),  64 KB

// fast softplus: 2 trans + ~4 VALU. exact for x>20; inputs are ~N(0,1).
__device__ __forceinline__ float softplus_f(float x) {
    float t = __expf(x);
    float r = 0.69314718056f * __log2f(1.0f + t);
    return (x > 20.0f) ? x : r;
}
// hw trig: v_sin/v_cos compute sin/cos(2*pi*x), x in revolutions.
__device__ __forceinline__ float sin_rev(float x) { return __builtin_amdgcn_sinf(x); }
__device__ __forceinline__ float cos_rev(float x) { return __builtin_amdgcn_cosf(x); }
__device__ __forceinline__ float fract_f(float x) { return __builtin_amdgcn_fractf(x); }
// block-uniform float -> SGPR
__device__ __forceinline__ float rfl(float x) {
    return __int_as_float(__builtin_amdgcn_readfirstlane(__float_as_int(x)));
}

// ---------------------------------------------------------------------------
// Fused FFT: softplus(H) + 64x64 Cooley-Tukey DFT -> g_Hft. Side-job (blocks
// 0..31): per-(n,d) trig table {step rot, mirror weights, w, tau} so the main
// kernel does NO m-independent trig.
// ---------------------------------------------------------------------------
__global__ void fft_fused(const float* __restrict__ H,
                          const float* __restrict__ W,
                          const float* __restrict__ tau) {
    __shared__ float  sHs[M_COLS];        // 16 KB
    __shared__ float2 sY[4 * 64];         // [j][k0], 2 KB

    int tid = threadIdx.x;
    int d   = blockIdx.x >> 4;
    int m0b = (blockIdx.x & 15) << 2;

    if (blockIdx.x < 32) {                // table side-job (no dependency)
        int t = blockIdx.x * 256 + tid;   // (n,d) pair index < 8192
        float w  = softplus_f(W[t]);
        float tv = tau[t];
        float rv = fract_f(tv * ((float)M_STRIDE / (float)M_COLS));  // tv/4
        float4 t4;
        t4.x = cos_rev(rv);               // step = e^{+i 2pi tau*1024/M}
        t4.y = sin_rev(rv);
        float rc = fract_f(-tv);          // e^{-2pi i tau}
        t4.z = w * cos_rev(rc);           // wcr
        t4.w = w * sin_rev(rc);           // wci
        g_Tab4[t] = t4;
        g_Tab2[t] = make_float2(w, tv);
    }

    const float4* Hrow4 = (const float4*)(H + d * M_COLS);
    #pragma unroll
    for (int p = 0; p < 4; ++p) {
        int i = p * 256 + tid;            // 1024 float4 per row
        float4 h4 = Hrow4[i];
        sHs[i*4+0] = softplus_f(h4.x);
        sHs[i*4+1] = softplus_f(h4.y);
        sHs[i*4+2] = softplus_f(h4.z);
        sHs[i*4+3] = softplus_f(h4.w);
    }
    __syncthreads();

    {   // stage A
        int k0 = tid & 63, j = tid >> 6;
        int m0 = m0b + j;
        float mrev = (float)m0 * (1.0f / 64.0f);
        float rr =  cos_rev(mrev);
        float ri = -sin_rev(mrev);        // step = e^{-2pi i m0/64}
        float twr = 1.0f, twi = 0.0f;
        float ar = 0.0f, ai = 0.0f;
        #pragma unroll
        for (int k1 = 0; k1 < 64; ++k1) {
            float v = sHs[(k1 << 6) + k0];
            ar = fmaf(v, twr, ar);
            ai = fmaf(v, twi, ai);
            float nr = fmaf(twr, rr, -(twi * ri));
            twi      = fmaf(twr, ri,   twi * rr);
            twr = nr;
        }
        sY[(j << 6) + k0] = make_float2(ar, ai);
    }
    __syncthreads();

    {   // stage B
        int m1 = tid & 63, j = tid >> 6;
        int m  = (m1 << 6) + m0b + j;
        float mrev = (float)m * (1.0f / 4096.0f);
        float rr =  cos_rev(mrev);
        float ri = -sin_rev(mrev);        // step = e^{-2pi i m/4096}
        float twr = 1.0f, twi = 0.0f;
        float ar = 0.0f, ai = 0.0f;
        #pragma unroll
        for (int k0 = 0; k0 < 64; ++k0) {
            float2 y = sY[(j << 6) + k0];
            ar = fmaf(y.x, twr, fmaf(-y.y, twi, ar));
            ai = fmaf(y.x, twi, fmaf( y.y, twr, ai));
            float nr = fmaf(twr, rr, -(twi * ri));
            twi      = fmaf(twr, ri,   twi * rr);
            twr = nr;
        }
        g_Hft[d * M_COLS + m] = make_float2(ar, ai);
    }
}

// ---------------------------------------------------------------------------
// Main with Hermitian mirroring + precomputed per-(n,d) table.
// For m = 1+m0+j*1024 (m0 in [0,1024)):
//   u = e^{+i 2pi tau m/M}, zr = ur*hr + ui*hi, zi = ur*hi - ui*hr
//   Re V[n,m]      += ws * zr
//   Re V[n,4096-m] += wcr*zr + wci*zi       (R12-validated formulas)
// Setup per (r,d): 1 fract + 2 trans (base phasor only) — all else from table.
// grid (4,512) = 2048 blocks = 8 waves/SIMD; ~45 live VGPRs, no big arrays.
// ---------------------------------------------------------------------------
__global__ void shiftnmf_main(float* __restrict__ out) {
    int tid = threadIdx.x;
    int m0  = blockIdx.x * 256 + tid;     // 0..1023 ; m_j = 1 + m0 + j*1024
    int n0  = blockIdx.y * R_ROWS;

    float fm0 = (float)(1 + m0) * (1.0f / (float)M_COLS);

    float accm[R_ROWS][T_PTS];            // direct outputs, m
    float accx[R_ROWS][T_PTS];            // mirror outputs, 4096-m
    #pragma unroll
    for (int r = 0; r < R_ROWS; ++r)
        #pragma unroll
        for (int j = 0; j < T_PTS; ++j) { accm[r][j] = 0.0f; accx[r][j] = 0.0f; }

    #pragma unroll
    for (int d = 0; d < RANK; ++d) {
        float ur[R_ROWS], ui[R_ROWS];                 // unit phasor (per-lane)
        float vr[R_ROWS], vi[R_ROWS];                 // step (SGPR)
        float ws[R_ROWS], wcr[R_ROWS], wci[R_ROWS];   // weights (SGPR)
        #pragma unroll
        for (int r = 0; r < R_ROWS; ++r) {
            int nd = (n0 + r) * RANK + d;
            float4 t4 = g_Tab4[nd];                   // block-uniform
            float2 t2 = g_Tab2[nd];
            vr[r]  = rfl(t4.x);  vi[r]  = rfl(t4.y);
            wcr[r] = rfl(t4.z);  wci[r] = rfl(t4.w);
            ws[r]  = rfl(t2.x);
            float tv = rfl(t2.y);
            float r0 = fract_f(tv * fm0);             // only per-thread trig
            ur[r] = cos_rev(r0);                      // u = e^{+i 2pi tau m_0/M}
            ui[r] = sin_rev(r0);
        }

        const float2* hp = g_Hft + d * M_COLS + 1 + m0;
        #pragma unroll
        for (int j = 0; j < T_PTS; ++j) {
            float2 h = hp[j * M_STRIDE];              // coalesced, L2-resident
            #pragma unroll
            for (int r = 0; r < R_ROWS; ++r) {
                float t1 = ui[r] * h.y;
                float zr = fmaf(ur[r], h.x, t1);      // Re(conj(u)h)
                float t2v = ui[r] * h.x;
                float zi = fmaf(ur[r], h.y, -t2v);    // Im(conj(u)h)
                accm[r][j] = fmaf(ws[r],  zr, accm[r][j]);
                accx[r][j] = fmaf(wcr[r], zr, fmaf(wci[r], zi, accx[r][j]));
                if (j < T_PTS - 1) {                  // u *= v (skip dead last)
                    float nr = fmaf(ur[r], vr[r], -(ui[r] * vi[r]));
                    ui[r]    = fmaf(ur[r], vi[r],   ui[r] * vr[r]);
                    ur[r]    = nr;
                }
            }
        }
    }

    #pragma unroll
    for (int r = 0; r < R_ROWS; ++r) {
        float* op = out + (n0 + r) * M_COLS;
        #pragma unroll
        for (int j = 0; j < T_PTS; ++j)
            op[1 + m0 + j * M_STRIDE] = accm[r][j];    // m in [1,2048]
        #pragma unroll
        for (int j = 0; j < T_PTS; ++j)
            op[4095 - m0 - j * M_STRIDE] = accx[r][j]; // 4096-m in [2048,4095]
    }

    if (blockIdx.x == 0 && tid == 0) {                // column 0, direct
        #pragma unroll
        for (int r = 0; r < R_ROWS; ++r) {
            int n = n0 + r;
            float a = 0.0f;
            #pragma unroll
            for (int d = 0; d < RANK; ++d)
                a = fmaf(g_Tab2[n * RANK + d].x, g_Hft[d * M_COLS].x, a);
            out[n * M_COLS] = a;
        }
    }
}

extern "C" void kernel_launch(void* const* d_in, const int* in_sizes, int n_in,
                              void* d_out, int out_size, void* d_ws, size_t ws_size,
                              hipStream_t stream) {
    const float* W   = (const float*)d_in[0];   // [1024, 8]
    const float* H   = (const float*)d_in[1];   // [8, 4096]
    const float* tau = (const float*)d_in[2];   // [1024, 8]

    fft_fused<<<dim3(RANK * 16), dim3(256), 0, stream>>>(H, W, tau);

    dim3 grid(M_COLS / 2 / (256 * T_PTS), N_ROWS / R_ROWS);  // (4, 512)
    shiftnmf_main<<<grid, dim3(256), 0, stream>>>((float*)d_out);
}